// Round 1
// baseline (3930.546 us; speedup 1.0000x reference)
//
#include <hip/hip_runtime.h>
#include <math.h>

// Problem constants
#define B_    32
#define H_IN  161
#define W_IN  1024
#define C1_   32
#define H1_   81
#define W1_   512
#define C2_   32
#define H2_   41
#define W2_   512

// ws layout (floats)
#define XA_OFF   0
#define XA_SZ    ((size_t)B_ * H1_ * C1_ * W1_)            // 42,467,328
#define WT1_OFF  (XA_SZ)
#define WT1_SZ   (41 * 11 * 32)                            // 14,432
#define WT2_OFF  (WT1_OFF + WT1_SZ)
#define WT2_SZ   (32 * 21 * 11 * 32)                       // 236,544
#define SCSH_OFF (WT2_OFF + WT2_SZ)
#define SCSH_SZ  128
#define LENS1_OFF (SCSH_OFF + SCSH_SZ)

#define OUT_X_SZ ((size_t)B_ * C2_ * H2_ * W2_)            // 21,495,808

// ---------------------------------------------------------------------------
// Prep: transpose weights to [..,kh,kw,o] (uniform-addr float4 -> s_load),
// fold conv-bias+BN into per-channel scale/shift, compute lens, write lens out.
// ---------------------------------------------------------------------------
__global__ void prep_kernel(const float* __restrict__ w1, const float* __restrict__ b1,
                            const float* __restrict__ g1, const float* __restrict__ be1,
                            const float* __restrict__ m1, const float* __restrict__ v1,
                            const float* __restrict__ w2, const float* __restrict__ b2,
                            const float* __restrict__ g2, const float* __restrict__ be2,
                            const float* __restrict__ m2, const float* __restrict__ v2,
                            const int* __restrict__ lens,
                            float* __restrict__ wT1, float* __restrict__ wT2,
                            float* __restrict__ scsh, int* __restrict__ lens1,
                            float* __restrict__ out_lens)
{
    const int i = blockIdx.x * blockDim.x + threadIdx.x;
    const int stride = gridDim.x * blockDim.x;

    // wT2[c][kh][kw][o] = w2[o][c][kh][kw]
    for (int idx = i; idx < WT2_SZ; idx += stride) {
        int o  = idx & 31;
        int kw = (idx >> 5) % 11;
        int kh = (idx / (32 * 11)) % 21;
        int c  = idx / (32 * 11 * 21);
        wT2[idx] = w2[((o * 32 + c) * 21 + kh) * 11 + kw];
    }
    // wT1[kh][kw][o] = w1[o][kh][kw]
    for (int idx = i; idx < WT1_SZ; idx += stride) {
        int o  = idx & 31;
        int kw = (idx >> 5) % 11;
        int kh = idx / (32 * 11);
        wT1[idx] = w1[o * 451 + kh * 11 + kw];
    }
    if (i < 32) {
        float s1 = g1[i] / sqrtf(v1[i] + 1e-5f);
        scsh[i]      = s1;
        scsh[32 + i] = b1[i] * s1 + be1[i] - m1[i] * s1;
        float s2 = g2[i] / sqrtf(v2[i] + 1e-5f);
        scsh[64 + i] = s2;
        scsh[96 + i] = b2[i] * s2 + be2[i] - m2[i] * s2;
        int l1 = (lens[i] - 1) / 2 + 1;   // new_len for (k=11,s=2,p=5); lens>=1
        if (l1 > W1_) l1 = W1_;
        lens1[i] = l1;
        out_lens[i] = (float)l1;          // layer-2 new_len is identity
    }
}

// ---------------------------------------------------------------------------
// Conv1 fused: Conv2d(1,32,(41,11),(2,2),(20,5)) + bias + BN + hardtanh + mask
// Block: (b, h, 256-w tile). Thread: 1 w, 32 output channels.
// Writes xA in [b][h][c][w] layout for conv2 locality.
// ---------------------------------------------------------------------------
__global__ __launch_bounds__(256) void conv1_kernel(
    const float* __restrict__ x,     // [32][1][161][1024]
    const float* __restrict__ wT1,   // [41][11][32]
    const float* __restrict__ scsh,
    const int* __restrict__ lens1,
    float* __restrict__ xA)          // [32][81][32][512]
{
    const int t  = threadIdx.x;
    const int w0 = blockIdx.x * 256;       // 0 or 256
    const int h  = blockIdx.y;             // 0..80
    const int b  = blockIdx.z;             // 0..31

    __shared__ float sin_[8][524];         // 8 staged rows x 521 cols

    float acc[32];
#pragma unroll
    for (int o = 0; o < 32; ++o) acc[o] = 0.f;

    const int r_base = 2 * h - 20;
    const int cbase  = 2 * w0 - 5;
    const float* xb = x + (size_t)b * (H_IN * W_IN);

    for (int chunk = 0; chunk < 41; chunk += 8) {
        const int nrows = min(8, 41 - chunk);
        for (int rr = 0; rr < nrows; ++rr) {
            int r = r_base + chunk + rr;
            bool rv = (r >= 0 && r < H_IN);
            const float* src = xb + (size_t)r * W_IN;
            for (int i = t; i < 521; i += 256) {
                int col = cbase + i;
                float v = 0.f;
                if (rv && col >= 0 && col < W_IN) v = src[col];
                sin_[rr][i] = v;
            }
        }
        __syncthreads();
        for (int rr = 0; rr < nrows; ++rr) {
            const int kh = chunk + rr;
            float win[11];
#pragma unroll
            for (int i = 0; i < 11; ++i) win[i] = sin_[rr][2 * t + i];
            const float* wrow = wT1 + kh * (11 * 32);
#pragma unroll
            for (int kw = 0; kw < 11; ++kw) {
                const float4* wp = (const float4*)(wrow + kw * 32);
#pragma unroll
                for (int o4 = 0; o4 < 8; ++o4) {
                    float4 wv = wp[o4];
                    acc[o4 * 4 + 0] = fmaf(win[kw], wv.x, acc[o4 * 4 + 0]);
                    acc[o4 * 4 + 1] = fmaf(win[kw], wv.y, acc[o4 * 4 + 1]);
                    acc[o4 * 4 + 2] = fmaf(win[kw], wv.z, acc[o4 * 4 + 2]);
                    acc[o4 * 4 + 3] = fmaf(win[kw], wv.w, acc[o4 * 4 + 3]);
                }
            }
        }
        __syncthreads();
    }

    const int w = w0 + t;
    const int l1 = lens1[b];
    const bool keep = (w < l1);
    float* dst = xA + ((size_t)(b * H1_ + h) * C1_) * W1_ + w;
#pragma unroll
    for (int o = 0; o < 32; ++o) {
        float s  = scsh[o];
        float sh = scsh[32 + o];
        float v  = fminf(fmaxf(fmaf(acc[o], s, sh), 0.f), 20.f);
        dst[(size_t)o * W1_] = keep ? v : 0.f;
    }
}

// ---------------------------------------------------------------------------
// Conv2 fused: Conv2d(32,32,(21,11),(2,1),(10,5)) + bias + BN + hardtanh + mask
// Block: (b, h, 256-w tile). Thread: 1 w, 32 output channels.
// Per input channel: stage all 21 input rows in LDS, one barrier pair.
// ---------------------------------------------------------------------------
__global__ __launch_bounds__(256) void conv2_kernel(
    const float* __restrict__ xA,    // [32][81][32][512]
    const float* __restrict__ wT2,   // [32][21][11][32]
    const float* __restrict__ scsh,
    const int* __restrict__ lens1,
    float* __restrict__ out)         // [32][32][41][512]
{
    const int t  = threadIdx.x;
    const int w0 = blockIdx.x * 256;
    const int h  = blockIdx.y;             // 0..40
    const int b  = blockIdx.z;

    __shared__ float sin_[21][268];        // 21 rows x 266 cols

    float acc[32];
#pragma unroll
    for (int o = 0; o < 32; ++o) acc[o] = 0.f;

    const int r_base = 2 * h - 10;
    const int cb = w0 - 5;

    for (int c = 0; c < 32; ++c) {
        for (int kh = 0; kh < 21; ++kh) {
            int r = r_base + kh;
            bool rv = (r >= 0 && r < H1_);
            const float* src = xA + (((size_t)(b * H1_ + r)) * C1_ + c) * W1_;
            for (int i = t; i < 266; i += 256) {
                int col = cb + i;
                float v = 0.f;
                if (rv && col >= 0 && col < W1_) v = src[col];
                sin_[kh][i] = v;
            }
        }
        __syncthreads();
        const float* wc = wT2 + (size_t)c * (21 * 11 * 32);
        for (int kh = 0; kh < 21; ++kh) {
            int r = r_base + kh;
            if (r < 0 || r >= H1_) continue;      // block-uniform skip
            float win[11];
#pragma unroll
            for (int i = 0; i < 11; ++i) win[i] = sin_[kh][t + i];
            const float* wrow = wc + kh * (11 * 32);
#pragma unroll
            for (int kw = 0; kw < 11; ++kw) {
                const float4* wp = (const float4*)(wrow + kw * 32);
#pragma unroll
                for (int o4 = 0; o4 < 8; ++o4) {
                    float4 wv = wp[o4];
                    acc[o4 * 4 + 0] = fmaf(win[kw], wv.x, acc[o4 * 4 + 0]);
                    acc[o4 * 4 + 1] = fmaf(win[kw], wv.y, acc[o4 * 4 + 1]);
                    acc[o4 * 4 + 2] = fmaf(win[kw], wv.z, acc[o4 * 4 + 2]);
                    acc[o4 * 4 + 3] = fmaf(win[kw], wv.w, acc[o4 * 4 + 3]);
                }
            }
        }
        __syncthreads();
    }

    const int w = w0 + t;
    const int l2 = lens1[b];               // lens2 == lens1
    const bool keep = (w < l2);
    float* dst = out + ((size_t)b * C2_ * H2_ + h) * W2_ + w;
#pragma unroll
    for (int o = 0; o < 32; ++o) {
        float s  = scsh[64 + o];
        float sh = scsh[96 + o];
        float v  = fminf(fmaxf(fmaf(acc[o], s, sh), 0.f), 20.f);
        dst[(size_t)o * (H2_ * W2_)] = keep ? v : 0.f;
    }
}

// ---------------------------------------------------------------------------
extern "C" void kernel_launch(void* const* d_in, const int* in_sizes, int n_in,
                              void* d_out, int out_size, void* d_ws, size_t ws_size,
                              hipStream_t stream) {
    const float* inputs = (const float*)d_in[0];
    const int*   slen   = (const int*)d_in[1];
    const float* w1 = (const float*)d_in[2];
    const float* b1 = (const float*)d_in[3];
    const float* g1 = (const float*)d_in[4];
    const float* be1 = (const float*)d_in[5];
    const float* m1 = (const float*)d_in[6];
    const float* v1 = (const float*)d_in[7];
    const float* w2 = (const float*)d_in[8];
    const float* b2 = (const float*)d_in[9];
    const float* g2 = (const float*)d_in[10];
    const float* be2 = (const float*)d_in[11];
    const float* m2 = (const float*)d_in[12];
    const float* v2 = (const float*)d_in[13];

    float* ws = (float*)d_ws;
    float* xA   = ws + XA_OFF;
    float* wT1  = ws + WT1_OFF;
    float* wT2  = ws + WT2_OFF;
    float* scsh = ws + SCSH_OFF;
    int*   lens1 = (int*)(ws + LENS1_OFF);

    float* out_x    = (float*)d_out;
    float* out_lens = out_x + OUT_X_SZ;

    hipLaunchKernelGGL(prep_kernel, dim3(256), dim3(256), 0, stream,
                       w1, b1, g1, be1, m1, v1, w2, b2, g2, be2, m2, v2,
                       slen, wT1, wT2, scsh, lens1, out_lens);

    hipLaunchKernelGGL(conv1_kernel, dim3(2, H1_, B_), dim3(256), 0, stream,
                       inputs, wT1, scsh, lens1, xA);

    hipLaunchKernelGGL(conv2_kernel, dim3(2, H2_, B_), dim3(256), 0, stream,
                       xA, wT2, scsh, lens1, out_x);
}

// Round 2
// 800.103 us; speedup vs baseline: 4.9126x; 4.9126x over previous
//
#include <hip/hip_runtime.h>
#include <math.h>

// Problem constants
#define B_    32
#define H_IN  161
#define W_IN  1024
#define C1_   32
#define H1_   81
#define W1_   512
#define C2_   32
#define H2_   41
#define W2_   512

#define OUT_X_SZ ((size_t)B_ * C2_ * H2_ * W2_)            // 21,495,808

// ws byte offsets (all 16B-aligned)
#define WF2_B    0u            // 236544 bf16 = 473088 B (weights, A-frag order)
#define WT1_B    473088u       // 14432 fp32 = 57728 B
#define SCSH_B   530816u       // 128 fp32
#define LENS1_B  531328u       // 32 int
#define XG_B     531456u       // 32*81*512*32 bf16 = 84,934,656 B

#define WF2_N    236544        // 21*11*2 frags * 512 bf16

typedef __bf16 v8bf __attribute__((ext_vector_type(8)));
typedef float v16f __attribute__((ext_vector_type(16)));

static __device__ __forceinline__ unsigned short f2bf(float f) {
    unsigned int u = __float_as_uint(f);
    unsigned int r = (u + 0x7fffu + ((u >> 16) & 1u)) >> 16;
    return (unsigned short)r;
}

// ---------------------------------------------------------------------------
// Prep: pack conv2 weights into MFMA A-fragment lane order (bf16), transpose
// conv1 weights, fold BN, compute lens.
// ---------------------------------------------------------------------------
__global__ void prep_kernel(const float* __restrict__ w1, const float* __restrict__ b1,
                            const float* __restrict__ g1, const float* __restrict__ be1,
                            const float* __restrict__ m1, const float* __restrict__ v1,
                            const float* __restrict__ w2, const float* __restrict__ b2,
                            const float* __restrict__ g2, const float* __restrict__ be2,
                            const float* __restrict__ m2, const float* __restrict__ v2,
                            const int* __restrict__ lens,
                            float* __restrict__ wT1, unsigned short* __restrict__ wf2,
                            float* __restrict__ scsh, int* __restrict__ lens1,
                            float* __restrict__ out_lens)
{
    const int i = blockIdx.x * blockDim.x + threadIdx.x;
    const int stride = gridDim.x * blockDim.x;

    // wf2: frag f=(kh*11+kw)*2+ch, lane l, elem j  <-  w2[oc=l&31][c=ch*16+(l>>5)*8+j][kh][kw]
    for (int idx = i; idx < WF2_N; idx += stride) {
        int j  = idx & 7;
        int l  = (idx >> 3) & 63;
        int f  = idx >> 9;
        int ch = f & 1;
        int kwkh = f >> 1;
        int kw = kwkh % 11;
        int kh = kwkh / 11;
        int oc = l & 31;
        int c  = ch * 16 + ((l >> 5) << 3) + j;
        wf2[idx] = f2bf(w2[((oc * 32 + c) * 21 + kh) * 11 + kw]);
    }
    // wT1[kh][kw][o] = w1[o][kh][kw]
    for (int idx = i; idx < 41 * 11 * 32; idx += stride) {
        int o  = idx & 31;
        int kw = (idx >> 5) % 11;
        int kh = idx / (32 * 11);
        wT1[idx] = w1[o * 451 + kh * 11 + kw];
    }
    if (i < 32) {
        float s1 = g1[i] / sqrtf(v1[i] + 1e-5f);
        scsh[i]      = s1;
        scsh[32 + i] = b1[i] * s1 + be1[i] - m1[i] * s1;
        float s2 = g2[i] / sqrtf(v2[i] + 1e-5f);
        scsh[64 + i] = s2;
        scsh[96 + i] = b2[i] * s2 + be2[i] - m2[i] * s2;
        int l1 = (lens[i] - 1) / 2 + 1;
        if (l1 > W1_) l1 = W1_;
        lens1[i] = l1;
        out_lens[i] = (float)l1;
    }
}

// ---------------------------------------------------------------------------
// Conv1 fused (fp32 compute): writes bf16 xg[b][h][w][c]
// ---------------------------------------------------------------------------
__global__ __launch_bounds__(256) void conv1_kernel(
    const float* __restrict__ x,     // [32][1][161][1024]
    const float* __restrict__ wT1,   // [41][11][32]
    const float* __restrict__ scsh,
    const int* __restrict__ lens1,
    unsigned short* __restrict__ xg) // [32][81][512][32] bf16
{
    const int t  = threadIdx.x;
    const int w0 = blockIdx.x * 256;
    const int h  = blockIdx.y;
    const int b  = blockIdx.z;

    __shared__ float sin_[8][524];

    float acc[32];
#pragma unroll
    for (int o = 0; o < 32; ++o) acc[o] = 0.f;

    const int r_base = 2 * h - 20;
    const int cbase  = 2 * w0 - 5;
    const float* xb = x + (size_t)b * (H_IN * W_IN);

    for (int chunk = 0; chunk < 41; chunk += 8) {
        const int nrows = min(8, 41 - chunk);
        for (int rr = 0; rr < nrows; ++rr) {
            int r = r_base + chunk + rr;
            bool rv = (r >= 0 && r < H_IN);
            const float* src = xb + (size_t)r * W_IN;
            for (int i = t; i < 521; i += 256) {
                int col = cbase + i;
                float v = 0.f;
                if (rv && col >= 0 && col < W_IN) v = src[col];
                sin_[rr][i] = v;
            }
        }
        __syncthreads();
        for (int rr = 0; rr < nrows; ++rr) {
            const int kh = chunk + rr;
            float win[11];
#pragma unroll
            for (int i = 0; i < 11; ++i) win[i] = sin_[rr][2 * t + i];
            const float* wrow = wT1 + kh * (11 * 32);
#pragma unroll
            for (int kw = 0; kw < 11; ++kw) {
                const float4* wp = (const float4*)(wrow + kw * 32);
#pragma unroll
                for (int o4 = 0; o4 < 8; ++o4) {
                    float4 wv = wp[o4];
                    acc[o4 * 4 + 0] = fmaf(win[kw], wv.x, acc[o4 * 4 + 0]);
                    acc[o4 * 4 + 1] = fmaf(win[kw], wv.y, acc[o4 * 4 + 1]);
                    acc[o4 * 4 + 2] = fmaf(win[kw], wv.z, acc[o4 * 4 + 2]);
                    acc[o4 * 4 + 3] = fmaf(win[kw], wv.w, acc[o4 * 4 + 3]);
                }
            }
        }
        __syncthreads();
    }

    const int w = w0 + t;
    const int l1 = lens1[b];
    const bool keep = (w < l1);

    uint4* dst = (uint4*)(xg + (((size_t)b * H1_ + h) * W1_ + w) * 32);
#pragma unroll
    for (int q = 0; q < 4; ++q) {
        unsigned int wd[4];
#pragma unroll
        for (int d = 0; d < 4; ++d) {
            int o = q * 8 + d * 2;
            float va = fminf(fmaxf(fmaf(acc[o],     scsh[o],     scsh[32 + o]), 0.f), 20.f);
            float vb = fminf(fmaxf(fmaf(acc[o + 1], scsh[o + 1], scsh[33 + o]), 0.f), 20.f);
            if (!keep) { va = 0.f; vb = 0.f; }
            wd[d] = (unsigned int)f2bf(va) | ((unsigned int)f2bf(vb) << 16);
        }
        uint4 u; u.x = wd[0]; u.y = wd[1]; u.z = wd[2]; u.w = wd[3];
        dst[q] = u;
    }
}

// ---------------------------------------------------------------------------
// Conv2 via bf16 MFMA implicit GEMM.
// Block: (b, h, 256 w), 4 waves x (2 n-tiles of 32 w). acc 32x32 per wave-tile.
// LDS: input row [w5][c] bf16, stride 80B, double-buffered (2x21280B).
// A (weights) streamed from global in frag order (L1-hot). B from LDS.
// ---------------------------------------------------------------------------
#define ROWB 21280   // 266 * 80

__global__ __launch_bounds__(256, 3) void conv2_mfma(
    const unsigned short* __restrict__ xg,   // [32][81][512][32] bf16
    const unsigned short* __restrict__ wf2,  // frag-ordered
    const float* __restrict__ scsh,
    const int* __restrict__ lens1,
    float* __restrict__ out)                 // [32][32][41][512] fp32
{
    const int t    = threadIdx.x;
    const int lane = t & 63;
    const int l31  = lane & 31;
    const int lhi  = lane >> 5;
    const int wv   = t >> 6;
    const int w0B  = blockIdx.x * 256;
    const int h    = blockIdx.y;
    const int b    = blockIdx.z;

    __shared__ __align__(16) char sbuf[2 * ROWB];

    v16f acc0, acc1;
#pragma unroll
    for (int i = 0; i < 16; ++i) { acc0[i] = 0.f; acc1[i] = 0.f; }

    // staging addresses: element i = t + it*256, i<1064; w5=i>>2, chunk=i&3
    const int st_lds = (t >> 2) * 80 + (t & 3) * 16;
    // B-frag read base: lane l31 -> w5 = wv*64 + l31 (+nt*32 +kw), chunk lhi (+ch*2)
    const int rd_lds = (wv * 64 + l31) * 80 + lhi * 16;

    const unsigned short* xb = xg + (size_t)b * (H1_ * W1_ * 32);
    const int r0 = 2 * h - 10;

    // ---- prologue: stage row for kh=0 ----
    {
        int r = r0;
        if (r >= 0 && r < H1_) {
            const unsigned short* xrow = xb + (size_t)r * (W1_ * 32);
#pragma unroll
            for (int it = 0; it < 5; ++it) {
                int i = t + it * 256;
                int wp = (i >> 2) + w0B - 5;
                uint4 z; z.x = z.y = z.z = z.w = 0u;
                if (i < 1064 && wp >= 0 && wp < W1_)
                    z = *(const uint4*)(xrow + (size_t)wp * 32 + (i & 3) * 8);
                if (i < 1064)
                    *(uint4*)(sbuf + st_lds + it * 5120) = z;
            }
        }
    }
    __syncthreads();

    for (int kh = 0; kh < 21; ++kh) {
        const int p = kh & 1;
        const int rn = r0 + kh + 1;
        const bool stage_next = (kh < 20) && (rn >= 0) && (rn < H1_);

        // issue staging loads for next row (hidden under MFMAs)
        uint4 g0, g1, g2, g3, g4;
        g0.x=g0.y=g0.z=g0.w=0u; g1=g0; g2=g0; g3=g0; g4=g0;
        if (stage_next) {
            const unsigned short* xrow = xb + (size_t)rn * (W1_ * 32);
            const int wbase = (t >> 2) + w0B - 5;
            const int ck = (t & 3) * 8;
            if (wbase >= 0 && wbase < W1_)                 g0 = *(const uint4*)(xrow + (size_t)wbase * 32 + ck);
            if (wbase + 64 >= 0 && wbase + 64 < W1_)       g1 = *(const uint4*)(xrow + (size_t)(wbase + 64) * 32 + ck);
            if (wbase + 128 < W1_)                         g2 = *(const uint4*)(xrow + (size_t)(wbase + 128) * 32 + ck);
            if (wbase + 192 < W1_)                         g3 = *(const uint4*)(xrow + (size_t)(wbase + 192) * 32 + ck);
            if (t < 40 && wbase + 256 < W1_)               g4 = *(const uint4*)(xrow + (size_t)(wbase + 256) * 32 + ck);
        }

        // compute on buffer p
        const int r = r0 + kh;
        if (r >= 0 && r < H1_) {
            const unsigned short* wkh = wf2 + kh * (22 * 512);
            const char* bbase = sbuf + p * ROWB + rd_lds;
#pragma unroll
            for (int kw = 0; kw < 11; ++kw) {
#pragma unroll
                for (int ch = 0; ch < 2; ++ch) {
                    uint4 a_u = *((const uint4*)(wkh + ((kw * 2 + ch) << 9)) + lane);
                    uint4 b0_u = *(const uint4*)(bbase + kw * 80 + ch * 32);
                    uint4 b1_u = *(const uint4*)(bbase + 2560 + kw * 80 + ch * 32);
                    v8bf a  = __builtin_bit_cast(v8bf, a_u);
                    v8bf bb0 = __builtin_bit_cast(v8bf, b0_u);
                    v8bf bb1 = __builtin_bit_cast(v8bf, b1_u);
                    acc0 = __builtin_amdgcn_mfma_f32_32x32x16_bf16(a, bb0, acc0, 0, 0, 0);
                    acc1 = __builtin_amdgcn_mfma_f32_32x32x16_bf16(a, bb1, acc1, 0, 0, 0);
                }
            }
        }

        // write next row into buffer p^1
        if (stage_next) {
            char* wb = sbuf + (p ^ 1) * ROWB + st_lds;
            *(uint4*)(wb)            = g0;
            *(uint4*)(wb + 5120)     = g1;
            *(uint4*)(wb + 2 * 5120) = g2;
            *(uint4*)(wb + 3 * 5120) = g3;
            if (t < 40) *(uint4*)(wb + 4 * 5120) = g4;
        }
        __syncthreads();
    }

    // ---- epilogue ----
    const int l2 = lens1[b];
#pragma unroll
    for (int nt = 0; nt < 2; ++nt) {
        const int w = w0B + wv * 64 + nt * 32 + l31;
        const bool keep = (w < l2);
#pragma unroll
        for (int reg = 0; reg < 16; ++reg) {
            int oc = (reg & 3) + 8 * (reg >> 2) + 4 * lhi;
            float av = (nt == 0) ? acc0[reg] : acc1[reg];
            float v = fmaf(av, scsh[64 + oc], scsh[96 + oc]);
            v = fminf(fmaxf(v, 0.f), 20.f);
            out[(((size_t)b * C2_ + oc) * H2_ + h) * W2_ + w] = keep ? v : 0.f;
        }
    }
}

// ---------------------------------------------------------------------------
extern "C" void kernel_launch(void* const* d_in, const int* in_sizes, int n_in,
                              void* d_out, int out_size, void* d_ws, size_t ws_size,
                              hipStream_t stream) {
    const float* inputs = (const float*)d_in[0];
    const int*   slen   = (const int*)d_in[1];
    const float* w1 = (const float*)d_in[2];
    const float* b1 = (const float*)d_in[3];
    const float* g1 = (const float*)d_in[4];
    const float* be1 = (const float*)d_in[5];
    const float* m1 = (const float*)d_in[6];
    const float* v1 = (const float*)d_in[7];
    const float* w2 = (const float*)d_in[8];
    const float* b2 = (const float*)d_in[9];
    const float* g2 = (const float*)d_in[10];
    const float* be2 = (const float*)d_in[11];
    const float* m2 = (const float*)d_in[12];
    const float* v2 = (const float*)d_in[13];

    char* ws = (char*)d_ws;
    unsigned short* wf2  = (unsigned short*)(ws + WF2_B);
    float*          wT1  = (float*)(ws + WT1_B);
    float*          scsh = (float*)(ws + SCSH_B);
    int*            lens1 = (int*)(ws + LENS1_B);
    unsigned short* xg   = (unsigned short*)(ws + XG_B);

    float* out_x    = (float*)d_out;
    float* out_lens = out_x + OUT_X_SZ;

    hipLaunchKernelGGL(prep_kernel, dim3(256), dim3(256), 0, stream,
                       w1, b1, g1, be1, m1, v1, w2, b2, g2, be2, m2, v2,
                       slen, wT1, wf2, scsh, lens1, out_lens);

    hipLaunchKernelGGL(conv1_kernel, dim3(2, H1_, B_), dim3(256), 0, stream,
                       inputs, wT1, scsh, lens1, xg);

    hipLaunchKernelGGL(conv2_mfma, dim3(2, H2_, B_), dim3(256), 0, stream,
                       xg, wf2, scsh, lens1, out_x);
}

// Round 3
// 523.581 us; speedup vs baseline: 7.5071x; 1.5281x over previous
//
#include <hip/hip_runtime.h>
#include <math.h>

// Problem constants
#define B_    32
#define H_IN  161
#define W_IN  1024
#define C1_   32
#define H1_   81
#define W1_   512
#define C2_   32
#define H2_   41
#define W2_   512

#define OUT_X_SZ ((size_t)B_ * C2_ * H2_ * W2_)            // 21,495,808

// ws byte offsets (all 16B-aligned)
#define WF2_B    0u            // 236544 bf16 (conv2 weights, A-frag order)
#define WF1_B    473088u       // 41*512 bf16 (conv1 weights, A-frag order, k 11->16 zero-pad)
#define SCSH_B   515072u       // 128 fp32
#define LENS1_B  515584u       // 32 int
#define XG_B     515712u       // 32*81*512*32 bf16 = 84,934,656 B

#define WF2_N    236544
#define WF1_N    20992         // 41 * 512

typedef __bf16 v8bf __attribute__((ext_vector_type(8)));
typedef float v16f __attribute__((ext_vector_type(16)));

static __device__ __forceinline__ unsigned short f2bf(float f) {
    unsigned int u = __float_as_uint(f);
    unsigned int r = (u + 0x7fffu + ((u >> 16) & 1u)) >> 16;
    return (unsigned short)r;
}

// ---------------------------------------------------------------------------
// Prep: pack conv1+conv2 weights into MFMA A-fragment lane order (bf16),
// fold BN, compute lens.
// ---------------------------------------------------------------------------
__global__ void prep_kernel(const float* __restrict__ w1, const float* __restrict__ b1,
                            const float* __restrict__ g1, const float* __restrict__ be1,
                            const float* __restrict__ m1, const float* __restrict__ v1,
                            const float* __restrict__ w2, const float* __restrict__ b2,
                            const float* __restrict__ g2, const float* __restrict__ be2,
                            const float* __restrict__ m2, const float* __restrict__ v2,
                            const int* __restrict__ lens,
                            unsigned short* __restrict__ wf1, unsigned short* __restrict__ wf2,
                            float* __restrict__ scsh, int* __restrict__ lens1,
                            float* __restrict__ out_lens)
{
    const int i = blockIdx.x * blockDim.x + threadIdx.x;
    const int stride = gridDim.x * blockDim.x;

    // wf2: frag f=(kh*11+kw)*2+ch, lane l, elem j <- w2[oc=l&31][c=ch*16+(l>>5)*8+j][kh][kw]
    for (int idx = i; idx < WF2_N; idx += stride) {
        int j  = idx & 7;
        int l  = (idx >> 3) & 63;
        int f  = idx >> 9;
        int ch = f & 1;
        int kwkh = f >> 1;
        int kw = kwkh % 11;
        int kh = kwkh / 11;
        int oc = l & 31;
        int c  = ch * 16 + ((l >> 5) << 3) + j;
        wf2[idx] = f2bf(w2[((oc * 32 + c) * 21 + kh) * 11 + kw]);
    }
    // wf1: frag kh, lane l, elem j <- w1[oc=l&31][kh][k=(l>>5)*8+j], zero for k>=11
    for (int idx = i; idx < WF1_N; idx += stride) {
        int j  = idx & 7;
        int l  = (idx >> 3) & 63;
        int kh = idx >> 9;
        int k  = ((l >> 5) << 3) + j;
        int oc = l & 31;
        wf1[idx] = (k < 11) ? f2bf(w1[oc * 451 + kh * 11 + k]) : (unsigned short)0;
    }
    if (i < 32) {
        float s1 = g1[i] / sqrtf(v1[i] + 1e-5f);
        scsh[i]      = s1;
        scsh[32 + i] = b1[i] * s1 + be1[i] - m1[i] * s1;
        float s2 = g2[i] / sqrtf(v2[i] + 1e-5f);
        scsh[64 + i] = s2;
        scsh[96 + i] = b2[i] * s2 + be2[i] - m2[i] * s2;
        int l1 = (lens[i] - 1) / 2 + 1;
        if (l1 > W1_) l1 = W1_;
        lens1[i] = l1;
        out_lens[i] = (float)l1;
    }
}

// ---------------------------------------------------------------------------
// Conv1 via bf16 MFMA implicit GEMM. One mfma_32x32x16 per kh (k=kw, 11
// taps + 5 zero-pad). Block: (b, h, 256 w); 4 waves x 2 n-tiles of 32 w.
// LDS: one 526-elem bf16 input row, double-buffered.
// Writes bf16 xg[b][h][w][c] (conv2's layout), fused BN+clip+mask.
// ---------------------------------------------------------------------------
__global__ __launch_bounds__(256) void conv1_mfma(
    const float* __restrict__ x,             // [32][1][161][1024]
    const unsigned short* __restrict__ wf1,  // frag-ordered
    const float* __restrict__ scsh,
    const int* __restrict__ lens1,
    unsigned short* __restrict__ xg)         // [32][81][512][32] bf16
{
    const int t    = threadIdx.x;
    const int lane = t & 63;
    const int l31  = lane & 31;
    const int lhi  = lane >> 5;
    const int wv   = t >> 6;
    const int w0   = blockIdx.x * 256;
    const int h    = blockIdx.y;
    const int b    = blockIdx.z;

    __shared__ unsigned int srow[2][264];    // 264 uints = 528 bf16 per buffer

    v16f acc0, acc1;
#pragma unroll
    for (int i = 0; i < 16; ++i) { acc0[i] = 0.f; acc1[i] = 0.f; }

    const int r0 = 2 * h - 20;
    const int cb = 2 * w0 - 5;               // global col of staged elem 0
    const float* xb = x + (size_t)b * (H_IN * W_IN);

    // dword read base for B frags: dw = wloc + 4*lhi
    const int dwbase = wv * 64 + l31 + 4 * lhi;

    // ---- prologue: stage row r0 into buffer 0 ----
    {
        float a0 = 0.f, a1 = 0.f, c0v = 0.f, c1v = 0.f;
        if (r0 >= 0 && r0 < H_IN) {
            const float* src = xb + (size_t)r0 * W_IN;
            int c0 = cb + 2 * t;
            if ((unsigned)c0 < (unsigned)W_IN)       a0 = src[c0];
            if ((unsigned)(c0 + 1) < (unsigned)W_IN) a1 = src[c0 + 1];
            if (t < 7) {
                int c1 = cb + 2 * (256 + t);
                if ((unsigned)c1 < (unsigned)W_IN)       c0v = src[c1];
                if ((unsigned)(c1 + 1) < (unsigned)W_IN) c1v = src[c1 + 1];
            }
        }
        srow[0][t] = (unsigned int)f2bf(a0) | ((unsigned int)f2bf(a1) << 16);
        if (t < 7)
            srow[0][256 + t] = (unsigned int)f2bf(c0v) | ((unsigned int)f2bf(c1v) << 16);
    }
    __syncthreads();

    for (int kh = 0; kh < 41; ++kh) {
        const int p = kh & 1;
        const int rn = r0 + kh + 1;
        const bool rv = (kh < 40) && (rn >= 0) && (rn < H_IN);

        // issue next-row staging loads (hidden under MFMAs)
        float a0 = 0.f, a1 = 0.f, c0v = 0.f, c1v = 0.f;
        if (rv) {
            const float* src = xb + (size_t)rn * W_IN;
            int c0 = cb + 2 * t;
            if ((unsigned)c0 < (unsigned)W_IN)       a0 = src[c0];
            if ((unsigned)(c0 + 1) < (unsigned)W_IN) a1 = src[c0 + 1];
            if (t < 7) {
                int c1 = cb + 2 * (256 + t);
                if ((unsigned)c1 < (unsigned)W_IN)       c0v = src[c1];
                if ((unsigned)(c1 + 1) < (unsigned)W_IN) c1v = src[c1 + 1];
            }
        }

        // compute on buffer p
        const int r = r0 + kh;
        if (r >= 0 && r < H_IN) {
            uint4 a_u = *((const uint4*)wf1 + kh * 32 + lane);
            v8bf a = __builtin_bit_cast(v8bf, a_u);
            const unsigned int* bp = &srow[p][0];
            {
                int dw = dwbase;
                uint4 bu;
                bu.x = bp[dw]; bu.y = bp[dw + 1]; bu.z = bp[dw + 2]; bu.w = bp[dw + 3];
                v8bf bb = __builtin_bit_cast(v8bf, bu);
                acc0 = __builtin_amdgcn_mfma_f32_32x32x16_bf16(a, bb, acc0, 0, 0, 0);
            }
            {
                int dw = dwbase + 32;
                uint4 bu;
                bu.x = bp[dw]; bu.y = bp[dw + 1]; bu.z = bp[dw + 2]; bu.w = bp[dw + 3];
                v8bf bb = __builtin_bit_cast(v8bf, bu);
                acc1 = __builtin_amdgcn_mfma_f32_32x32x16_bf16(a, bb, acc1, 0, 0, 0);
            }
        }

        // write staged row into buffer p^1
        if (rv) {
            srow[p ^ 1][t] = (unsigned int)f2bf(a0) | ((unsigned int)f2bf(a1) << 16);
            if (t < 7)
                srow[p ^ 1][256 + t] = (unsigned int)f2bf(c0v) | ((unsigned int)f2bf(c1v) << 16);
        }
        __syncthreads();
    }

    // ---- epilogue: BN + hardtanh + mask, write xg[b][h][w][c] bf16 ----
    const int l1 = lens1[b];
#pragma unroll
    for (int nt = 0; nt < 2; ++nt) {
        const int w = w0 + wv * 64 + nt * 32 + l31;
        const bool keep = (w < l1);
        unsigned short* dp = xg + (((size_t)b * H1_ + h) * W1_ + w) * 32;
#pragma unroll
        for (int rq = 0; rq < 4; ++rq) {
            unsigned int wd[2];
#pragma unroll
            for (int d = 0; d < 2; ++d) {
                int rg = rq * 4 + d * 2;
                int oc = 8 * rq + 4 * lhi + d * 2;
                float av0 = (nt == 0) ? acc0[rg]     : acc1[rg];
                float av1 = (nt == 0) ? acc0[rg + 1] : acc1[rg + 1];
                float v0 = fminf(fmaxf(fmaf(av0, scsh[oc],     scsh[32 + oc]), 0.f), 20.f);
                float v1 = fminf(fmaxf(fmaf(av1, scsh[oc + 1], scsh[33 + oc]), 0.f), 20.f);
                if (!keep) { v0 = 0.f; v1 = 0.f; }
                wd[d] = (unsigned int)f2bf(v0) | ((unsigned int)f2bf(v1) << 16);
            }
            uint2 u; u.x = wd[0]; u.y = wd[1];
            *(uint2*)(dp + 8 * rq + 4 * lhi) = u;
        }
    }
}

// ---------------------------------------------------------------------------
// Conv2 via bf16 MFMA implicit GEMM (unchanged from round 2).
// ---------------------------------------------------------------------------
#define ROWB 21280   // 266 * 80

__global__ __launch_bounds__(256, 3) void conv2_mfma(
    const unsigned short* __restrict__ xg,   // [32][81][512][32] bf16
    const unsigned short* __restrict__ wf2,  // frag-ordered
    const float* __restrict__ scsh,
    const int* __restrict__ lens1,
    float* __restrict__ out)                 // [32][32][41][512] fp32
{
    const int t    = threadIdx.x;
    const int lane = t & 63;
    const int l31  = lane & 31;
    const int lhi  = lane >> 5;
    const int wv   = t >> 6;
    const int w0B  = blockIdx.x * 256;
    const int h    = blockIdx.y;
    const int b    = blockIdx.z;

    __shared__ __align__(16) char sbuf[2 * ROWB];

    v16f acc0, acc1;
#pragma unroll
    for (int i = 0; i < 16; ++i) { acc0[i] = 0.f; acc1[i] = 0.f; }

    const int st_lds = (t >> 2) * 80 + (t & 3) * 16;
    const int rd_lds = (wv * 64 + l31) * 80 + lhi * 16;

    const unsigned short* xb = xg + (size_t)b * (H1_ * W1_ * 32);
    const int r0 = 2 * h - 10;

    {
        int r = r0;
        if (r >= 0 && r < H1_) {
            const unsigned short* xrow = xb + (size_t)r * (W1_ * 32);
#pragma unroll
            for (int it = 0; it < 5; ++it) {
                int i = t + it * 256;
                int wp = (i >> 2) + w0B - 5;
                uint4 z; z.x = z.y = z.z = z.w = 0u;
                if (i < 1064 && wp >= 0 && wp < W1_)
                    z = *(const uint4*)(xrow + (size_t)wp * 32 + (i & 3) * 8);
                if (i < 1064)
                    *(uint4*)(sbuf + st_lds + it * 5120) = z;
            }
        }
    }
    __syncthreads();

    for (int kh = 0; kh < 21; ++kh) {
        const int p = kh & 1;
        const int rn = r0 + kh + 1;
        const bool stage_next = (kh < 20) && (rn >= 0) && (rn < H1_);

        uint4 g0, g1, g2, g3, g4;
        g0.x=g0.y=g0.z=g0.w=0u; g1=g0; g2=g0; g3=g0; g4=g0;
        if (stage_next) {
            const unsigned short* xrow = xb + (size_t)rn * (W1_ * 32);
            const int wbase = (t >> 2) + w0B - 5;
            const int ck = (t & 3) * 8;
            if (wbase >= 0 && wbase < W1_)                 g0 = *(const uint4*)(xrow + (size_t)wbase * 32 + ck);
            if (wbase + 64 >= 0 && wbase + 64 < W1_)       g1 = *(const uint4*)(xrow + (size_t)(wbase + 64) * 32 + ck);
            if (wbase + 128 < W1_)                         g2 = *(const uint4*)(xrow + (size_t)(wbase + 128) * 32 + ck);
            if (wbase + 192 < W1_)                         g3 = *(const uint4*)(xrow + (size_t)(wbase + 192) * 32 + ck);
            if (t < 40 && wbase + 256 < W1_)               g4 = *(const uint4*)(xrow + (size_t)(wbase + 256) * 32 + ck);
        }

        const int r = r0 + kh;
        if (r >= 0 && r < H1_) {
            const unsigned short* wkh = wf2 + kh * (22 * 512);
            const char* bbase = sbuf + p * ROWB + rd_lds;
#pragma unroll
            for (int kw = 0; kw < 11; ++kw) {
#pragma unroll
                for (int ch = 0; ch < 2; ++ch) {
                    uint4 a_u = *((const uint4*)(wkh + ((kw * 2 + ch) << 9)) + lane);
                    uint4 b0_u = *(const uint4*)(bbase + kw * 80 + ch * 32);
                    uint4 b1_u = *(const uint4*)(bbase + 2560 + kw * 80 + ch * 32);
                    v8bf a  = __builtin_bit_cast(v8bf, a_u);
                    v8bf bb0 = __builtin_bit_cast(v8bf, b0_u);
                    v8bf bb1 = __builtin_bit_cast(v8bf, b1_u);
                    acc0 = __builtin_amdgcn_mfma_f32_32x32x16_bf16(a, bb0, acc0, 0, 0, 0);
                    acc1 = __builtin_amdgcn_mfma_f32_32x32x16_bf16(a, bb1, acc1, 0, 0, 0);
                }
            }
        }

        if (stage_next) {
            char* wb = sbuf + (p ^ 1) * ROWB + st_lds;
            *(uint4*)(wb)            = g0;
            *(uint4*)(wb + 5120)     = g1;
            *(uint4*)(wb + 2 * 5120) = g2;
            *(uint4*)(wb + 3 * 5120) = g3;
            if (t < 40) *(uint4*)(wb + 4 * 5120) = g4;
        }
        __syncthreads();
    }

    const int l2 = lens1[b];
#pragma unroll
    for (int nt = 0; nt < 2; ++nt) {
        const int w = w0B + wv * 64 + nt * 32 + l31;
        const bool keep = (w < l2);
#pragma unroll
        for (int reg = 0; reg < 16; ++reg) {
            int oc = (reg & 3) + 8 * (reg >> 2) + 4 * lhi;
            float av = (nt == 0) ? acc0[reg] : acc1[reg];
            float v = fmaf(av, scsh[64 + oc], scsh[96 + oc]);
            v = fminf(fmaxf(v, 0.f), 20.f);
            out[(((size_t)b * C2_ + oc) * H2_ + h) * W2_ + w] = keep ? v : 0.f;
        }
    }
}

// ---------------------------------------------------------------------------
extern "C" void kernel_launch(void* const* d_in, const int* in_sizes, int n_in,
                              void* d_out, int out_size, void* d_ws, size_t ws_size,
                              hipStream_t stream) {
    const float* inputs = (const float*)d_in[0];
    const int*   slen   = (const int*)d_in[1];
    const float* w1 = (const float*)d_in[2];
    const float* b1 = (const float*)d_in[3];
    const float* g1 = (const float*)d_in[4];
    const float* be1 = (const float*)d_in[5];
    const float* m1 = (const float*)d_in[6];
    const float* v1 = (const float*)d_in[7];
    const float* w2 = (const float*)d_in[8];
    const float* b2 = (const float*)d_in[9];
    const float* g2 = (const float*)d_in[10];
    const float* be2 = (const float*)d_in[11];
    const float* m2 = (const float*)d_in[12];
    const float* v2 = (const float*)d_in[13];

    char* ws = (char*)d_ws;
    unsigned short* wf2  = (unsigned short*)(ws + WF2_B);
    unsigned short* wf1  = (unsigned short*)(ws + WF1_B);
    float*          scsh = (float*)(ws + SCSH_B);
    int*            lens1 = (int*)(ws + LENS1_B);
    unsigned short* xg   = (unsigned short*)(ws + XG_B);

    float* out_x    = (float*)d_out;
    float* out_lens = out_x + OUT_X_SZ;

    hipLaunchKernelGGL(prep_kernel, dim3(256), dim3(256), 0, stream,
                       w1, b1, g1, be1, m1, v1, w2, b2, g2, be2, m2, v2,
                       slen, wf1, wf2, scsh, lens1, out_lens);

    hipLaunchKernelGGL(conv1_mfma, dim3(2, H1_, B_), dim3(256), 0, stream,
                       inputs, wf1, scsh, lens1, xg);

    hipLaunchKernelGGL(conv2_mfma, dim3(2, H2_, B_), dim3(256), 0, stream,
                       xg, wf2, scsh, lens1, out_x);
}